// Round 1
// baseline (1794.469 us; speedup 1.0000x reference)
//
#include <hip/hip_runtime.h>
#include <math.h>

#define HID    128
#define IN_CH  271
#define SEQ    281
#define NCLS   1854
#define BATCH  256
#define TBLK   5                      // ceil(281/64)
#define M_TOT  (SEQ * BATCH)          // 71936
#define XG_FLOATS ((size_t)M_TOT * 384)
#define H0_FLOATS ((size_t)M_TOT * HID)

// ---------------------------------------------------------------------------
// Kernel A1: XG[t,b,g*128+j] = sum_k X[b,k,t] * Wg0[k,j] + bg0[j]   (k<271)
// fp32 LDS-tiled GEMM. Block 128 threads computes 64 t x 128 j for one (b,g).
// ---------------------------------------------------------------------------
__global__ __launch_bounds__(128) void xg_l0(
    const float* __restrict__ X,
    const float* __restrict__ Wr, const float* __restrict__ Wu, const float* __restrict__ Wo,
    const float* __restrict__ br, const float* __restrict__ bu, const float* __restrict__ bo,
    float* __restrict__ XG)
{
    const int tb = blockIdx.x, b = blockIdx.y, g = blockIdx.z;
    const float* __restrict__ W    = (g == 0) ? Wr : (g == 1) ? Wu : Wo;
    const float* __restrict__ bias = (g == 0) ? br : (g == 1) ? bu : bo;

    __shared__ float Xt[16][64];
    __shared__ float Wt[16][128];

    const int i  = threadIdx.x;
    const int t0 = tb * 64;
    const float* __restrict__ Xb = X + (size_t)b * (IN_CH * SEQ);

    float acc[8][8];
#pragma unroll
    for (int x = 0; x < 8; ++x)
#pragma unroll
        for (int y = 0; y < 8; ++y) acc[x][y] = 0.f;

    const int tq = i >> 4;   // 0..7  -> t sub-block of 8
    const int jq = i & 15;   // 0..15 -> j sub-block of 8

    for (int k0 = 0; k0 < IN_CH; k0 += 16) {
        // stage X tile: 16k x 64t, coalesced along t
#pragma unroll
        for (int r = 0; r < 8; ++r) {
            int e = i + 128 * r;
            int kk = e >> 6, tt = e & 63;
            int k = k0 + kk, t = t0 + tt;
            Xt[kk][tt] = (k < IN_CH && t < SEQ) ? Xb[k * SEQ + t] : 0.f;
        }
        // stage W tile: 16k x 128j, coalesced along j
#pragma unroll
        for (int r = 0; r < 16; ++r) {
            int e = i + 128 * r;
            int kk = e >> 7, jj = e & 127;
            int k = k0 + kk;
            Wt[kk][jj] = (k < IN_CH) ? W[k * HID + jj] : 0.f;
        }
        __syncthreads();
#pragma unroll
        for (int kk = 0; kk < 16; ++kk) {
            float a[8], w[8];
#pragma unroll
            for (int x = 0; x < 8; ++x) a[x] = Xt[kk][tq * 8 + x];
#pragma unroll
            for (int y = 0; y < 8; ++y) w[y] = Wt[kk][jq * 8 + y];
#pragma unroll
            for (int x = 0; x < 8; ++x)
#pragma unroll
                for (int y = 0; y < 8; ++y) acc[x][y] += a[x] * w[y];
        }
        __syncthreads();
    }

#pragma unroll
    for (int x = 0; x < 8; ++x) {
        int t = t0 + tq * 8 + x;
        if (t < SEQ) {
            size_t base = ((size_t)t * BATCH + b) * 384 + g * HID + jq * 8;
#pragma unroll
            for (int y = 0; y < 8; ++y)
                XG[base + y] = acc[x][y] + bias[jq * 8 + y];
        }
    }
}

// ---------------------------------------------------------------------------
// Kernel A2: XG[m,g*128+j] = sum_k H0[m,k] * Wg1[k,j] + bg1[j]   (k<128,
// x-part rows of the [256,128] layer-1 weights). m = t*256+b, M=71936.
// ---------------------------------------------------------------------------
__global__ __launch_bounds__(128) void xg_l1(
    const float* __restrict__ H0,
    const float* __restrict__ Wr, const float* __restrict__ Wu, const float* __restrict__ Wo,
    const float* __restrict__ br, const float* __restrict__ bu, const float* __restrict__ bo,
    float* __restrict__ XG)
{
    const int mb = blockIdx.x, g = blockIdx.z;
    const float* __restrict__ W    = (g == 0) ? Wr : (g == 1) ? Wu : Wo;
    const float* __restrict__ bias = (g == 0) ? br : (g == 1) ? bu : bo;

    __shared__ float At[16][64];
    __shared__ float Wt[16][128];

    const int i  = threadIdx.x;
    const int m0 = mb * 64;

    float acc[8][8];
#pragma unroll
    for (int x = 0; x < 8; ++x)
#pragma unroll
        for (int y = 0; y < 8; ++y) acc[x][y] = 0.f;

    const int tq = i >> 4, jq = i & 15;

    for (int k0 = 0; k0 < HID; k0 += 16) {   // 8 full tiles, no remainder
#pragma unroll
        for (int r = 0; r < 8; ++r) {
            int e = i + 128 * r;
            int kk = e & 15, mm = e >> 4;
            At[kk][mm] = H0[(size_t)(m0 + mm) * HID + k0 + kk];
        }
#pragma unroll
        for (int r = 0; r < 16; ++r) {
            int e = i + 128 * r;
            int kk = e >> 7, jj = e & 127;
            Wt[kk][jj] = W[(k0 + kk) * HID + jj];
        }
        __syncthreads();
#pragma unroll
        for (int kk = 0; kk < 16; ++kk) {
            float a[8], w[8];
#pragma unroll
            for (int x = 0; x < 8; ++x) a[x] = At[kk][tq * 8 + x];
#pragma unroll
            for (int y = 0; y < 8; ++y) w[y] = Wt[kk][jq * 8 + y];
#pragma unroll
            for (int x = 0; x < 8; ++x)
#pragma unroll
                for (int y = 0; y < 8; ++y) acc[x][y] += a[x] * w[y];
        }
        __syncthreads();
    }

#pragma unroll
    for (int x = 0; x < 8; ++x) {
        int m = m0 + tq * 8 + x;     // always < 71936 (1124*64 exact)
        size_t base = (size_t)m * 384 + g * HID + jq * 8;
#pragma unroll
        for (int y = 0; y < 8; ++y)
            XG[base + y] = acc[x][y] + bias[jq * 8 + y];
    }
}

// ---------------------------------------------------------------------------
// Kernel B1: layer-0 recurrence. One block per batch element, 512 threads.
// Recurrent weights (rows 271..398) live in registers: thread (j = i&127,
// q = i>>7) holds W[271+q*32 .. +32][j]. h-state in LDS, LDS partial reduce.
// ---------------------------------------------------------------------------
__global__ __launch_bounds__(512, 2) void gru_l0(
    const float* __restrict__ Wr, const float* __restrict__ Wu, const float* __restrict__ Wo,
    const float* __restrict__ XG, float* __restrict__ H0)
{
    const int b = blockIdx.x;
    const int i = threadIdx.x;
    const int j = i & 127;
    const int q = i >> 7;

    __shared__ float h0[HID];
    __shared__ float rh[HID];
    __shared__ float ua[HID];
    __shared__ float P[2][4][HID];

    float wr[32], wu[32], wo[32];
    const int kbase = IN_CH + q * 32;
#pragma unroll
    for (int kk = 0; kk < 32; ++kk) {
        wr[kk] = Wr[(kbase + kk) * HID + j];
        wu[kk] = Wu[(kbase + kk) * HID + j];
        wo[kk] = Wo[(kbase + kk) * HID + j];
    }
    if (i < HID) h0[i] = 0.f;
    __syncthreads();

    for (int t = 0; t < SEQ; ++t) {
        const float* __restrict__ xg = XG + ((size_t)t * BATCH + b) * 384;

        // phase 1: r,u partials
        float hreg[32];
        {
            const float4* hp = (const float4*)(h0 + q * 32);
#pragma unroll
            for (int r = 0; r < 8; ++r) {
                float4 v = hp[r];
                hreg[4 * r] = v.x; hreg[4 * r + 1] = v.y;
                hreg[4 * r + 2] = v.z; hreg[4 * r + 3] = v.w;
            }
        }
        float pr = 0.f, pu = 0.f;
#pragma unroll
        for (int kk = 0; kk < 32; ++kk) {
            pr += wr[kk] * hreg[kk];
            pu += wu[kk] * hreg[kk];
        }
        P[0][q][j] = pr;
        P[1][q][j] = pu;
        __syncthreads();

        // phase 2: finish r,u; build rh = r*h0
        if (i < 256) {
            int g = i >> 7, jj = i & 127;
            float s = P[g][0][jj] + P[g][1][jj] + P[g][2][jj] + P[g][3][jj]
                    + xg[g * HID + jj];
            float v = 1.f / (1.f + __expf(-s));
            if (g == 0) rh[jj] = v * h0[jj];
            else        ua[jj] = v;
        }
        __syncthreads();

        // phase 3: o partials from rh
        float rreg[32];
        {
            const float4* rp = (const float4*)(rh + q * 32);
#pragma unroll
            for (int r = 0; r < 8; ++r) {
                float4 v = rp[r];
                rreg[4 * r] = v.x; rreg[4 * r + 1] = v.y;
                rreg[4 * r + 2] = v.z; rreg[4 * r + 3] = v.w;
            }
        }
        float po = 0.f;
#pragma unroll
        for (int kk = 0; kk < 32; ++kk) po += wo[kk] * rreg[kk];
        P[0][q][j] = po;
        __syncthreads();

        // phase 4: o = tanh, h update, store H0
        if (i < HID) {
            float s = P[0][0][i] + P[0][1][i] + P[0][2][i] + P[0][3][i]
                    + xg[2 * HID + i];
            float o = tanhf(s);
            float hn = h0[i] + ua[i] * (o - h0[i]);
            h0[i] = hn;
            H0[((size_t)t * BATCH + b) * HID + i] = hn;
        }
        __syncthreads();
    }
}

// ---------------------------------------------------------------------------
// Kernel B2: layer-1 recurrence (weights rows 128..255) + fused classifier.
// ---------------------------------------------------------------------------
__global__ __launch_bounds__(512, 2) void gru_l1(
    const float* __restrict__ Wr, const float* __restrict__ Wu, const float* __restrict__ Wo,
    const float* __restrict__ XG,
    const float* __restrict__ Wfc, const float* __restrict__ bfc,
    float* __restrict__ out)
{
    const int b = blockIdx.x;
    const int i = threadIdx.x;
    const int j = i & 127;
    const int q = i >> 7;

    __shared__ float h1[HID];
    __shared__ float rh[HID];
    __shared__ float ua[HID];
    __shared__ float P[2][4][HID];

    float wr[32], wu[32], wo[32];
    const int kbase = HID + q * 32;   // h-part rows of [256,128]
#pragma unroll
    for (int kk = 0; kk < 32; ++kk) {
        wr[kk] = Wr[(kbase + kk) * HID + j];
        wu[kk] = Wu[(kbase + kk) * HID + j];
        wo[kk] = Wo[(kbase + kk) * HID + j];
    }
    if (i < HID) h1[i] = 0.f;
    __syncthreads();

    for (int t = 0; t < SEQ; ++t) {
        const float* __restrict__ xg = XG + ((size_t)t * BATCH + b) * 384;

        float hreg[32];
        {
            const float4* hp = (const float4*)(h1 + q * 32);
#pragma unroll
            for (int r = 0; r < 8; ++r) {
                float4 v = hp[r];
                hreg[4 * r] = v.x; hreg[4 * r + 1] = v.y;
                hreg[4 * r + 2] = v.z; hreg[4 * r + 3] = v.w;
            }
        }
        float pr = 0.f, pu = 0.f;
#pragma unroll
        for (int kk = 0; kk < 32; ++kk) {
            pr += wr[kk] * hreg[kk];
            pu += wu[kk] * hreg[kk];
        }
        P[0][q][j] = pr;
        P[1][q][j] = pu;
        __syncthreads();

        if (i < 256) {
            int g = i >> 7, jj = i & 127;
            float s = P[g][0][jj] + P[g][1][jj] + P[g][2][jj] + P[g][3][jj]
                    + xg[g * HID + jj];
            float v = 1.f / (1.f + __expf(-s));
            if (g == 0) rh[jj] = v * h1[jj];
            else        ua[jj] = v;
        }
        __syncthreads();

        float rreg[32];
        {
            const float4* rp = (const float4*)(rh + q * 32);
#pragma unroll
            for (int r = 0; r < 8; ++r) {
                float4 v = rp[r];
                rreg[4 * r] = v.x; rreg[4 * r + 1] = v.y;
                rreg[4 * r + 2] = v.z; rreg[4 * r + 3] = v.w;
            }
        }
        float po = 0.f;
#pragma unroll
        for (int kk = 0; kk < 32; ++kk) po += wo[kk] * rreg[kk];
        P[0][q][j] = po;
        __syncthreads();

        if (i < HID) {
            float s = P[0][0][i] + P[0][1][i] + P[0][2][i] + P[0][3][i]
                    + xg[2 * HID + i];
            float o = tanhf(s);
            float hn = h1[i] + ua[i] * (o - h1[i]);
            h1[i] = hn;
        }
        __syncthreads();
    }

    // fused classifier: out[b,c] = sum_k h1[k] * Wfc[k,c] + bfc[c]
    const int c0 = i, c1 = i + 512, c2 = i + 1024;
    const int c3 = (i < NCLS - 1536) ? (i + 1536) : 0;   // clamped read, guarded store
    float a0 = bfc[c0], a1 = bfc[c1], a2 = bfc[c2], a3 = bfc[c3];
#pragma unroll 4
    for (int k = 0; k < HID; ++k) {
        float hk = h1[k];
        const float* __restrict__ wrow = Wfc + (size_t)k * NCLS;
        a0 += hk * wrow[c0];
        a1 += hk * wrow[c1];
        a2 += hk * wrow[c2];
        a3 += hk * wrow[c3];
    }
    float* orow = out + (size_t)b * NCLS;
    orow[c0] = a0;
    orow[c1] = a1;
    orow[c2] = a2;
    if (i < NCLS - 1536) orow[i + 1536] = a3;
}

// ---------------------------------------------------------------------------
extern "C" void kernel_launch(void* const* d_in, const int* in_sizes, int n_in,
                              void* d_out, int out_size, void* d_ws, size_t ws_size,
                              hipStream_t stream)
{
    const float* X   = (const float*)d_in[0];
    const float* Wr0 = (const float*)d_in[1];
    const float* br0 = (const float*)d_in[2];
    const float* Wu0 = (const float*)d_in[3];
    const float* bu0 = (const float*)d_in[4];
    const float* Wo0 = (const float*)d_in[5];
    const float* bo0 = (const float*)d_in[6];
    const float* Wr1 = (const float*)d_in[7];
    const float* br1 = (const float*)d_in[8];
    const float* Wu1 = (const float*)d_in[9];
    const float* bu1 = (const float*)d_in[10];
    const float* Wo1 = (const float*)d_in[11];
    const float* bo1 = (const float*)d_in[12];
    const float* Wfc = (const float*)d_in[13];
    const float* bfc = (const float*)d_in[14];
    float* out = (float*)d_out;

    float* XG = (float*)d_ws;           // 27,623,424 floats (reused for both layers)
    float* H0 = XG + XG_FLOATS;         //  9,207,808 floats
    // total ws requirement: 147,324,928 bytes (~140.5 MiB)

    xg_l0 <<<dim3(TBLK, BATCH, 3), 128, 0, stream>>>(X, Wr0, Wu0, Wo0, br0, bu0, bo0, XG);
    gru_l0<<<dim3(BATCH), 512, 0, stream>>>(Wr0, Wu0, Wo0, XG, H0);
    xg_l1 <<<dim3(M_TOT / 64, 1, 3), 128, 0, stream>>>(H0, Wr1, Wu1, Wo1, br1, bu1, bo1, XG);
    gru_l1<<<dim3(BATCH), 512, 0, stream>>>(Wr1, Wu1, Wo1, XG, Wfc, bfc, out);
}

// Round 2
// 1010.049 us; speedup vs baseline: 1.7766x; 1.7766x over previous
//
#include <hip/hip_runtime.h>
#include <math.h>

#define HID    128
#define IN_CH  271
#define SEQ    281
#define NCLS   1854
#define BATCH  256
#define M_TOT  (SEQ * BATCH)          // 71936 = 562 * 128
#define KPAD0  288                    // 271 padded to 9*32
#define KPAD1  128

typedef __attribute__((ext_vector_type(8))) short short8;
typedef __attribute__((ext_vector_type(4))) float floatx4;

__device__ __forceinline__ unsigned short f2bf(float f) {
    union { float f; unsigned u; } v; v.f = f;
    unsigned u = v.u;
    u += 0x7FFF + ((u >> 16) & 1);        // RNE
    return (unsigned short)(u >> 16);
}

// ---------------------------------------------------------------------------
// Transpose+convert X: X[b][k][t] fp32 -> Abf[(b*281+t)*288 + k] bf16,
// zero-padding k in [271,288).
// ---------------------------------------------------------------------------
__global__ __launch_bounds__(256) void xt_kernel(
    const float* __restrict__ X, unsigned short* __restrict__ Abf)
{
    const int tb = blockIdx.x;            // 0..4, t-tile of 64
    const int b  = blockIdx.y;
    const int tid = threadIdx.x;
    const int t0 = tb * 64;
    const float* __restrict__ Xb = X + (size_t)b * (IN_CH * SEQ);

    __shared__ float Xl[32][65];

    for (int kc = 0; kc < KPAD0 / 32; ++kc) {
        // load 32k x 64t, coalesced along t
#pragma unroll
        for (int r = 0; r < 8; ++r) {
            int e = tid + 256 * r;
            int kk = e >> 6, tt = e & 63;
            int k = kc * 32 + kk, t = t0 + tt;
            Xl[kk][tt] = (k < IN_CH && t < SEQ) ? Xb[k * SEQ + t] : 0.f;
        }
        __syncthreads();
        // store: 64t x 4 parts of 8 bf16 (16B per store), coalesced-ish along k
        {
            int tt = tid >> 2, part = tid & 3;
            int t = t0 + tt;
            if (t < SEQ) {
                union { unsigned short s[8]; uint4 v; } u;
#pragma unroll
                for (int i = 0; i < 8; ++i) u.s[i] = f2bf(Xl[part * 8 + i][tt]);
                *(uint4*)(Abf + ((size_t)b * SEQ + t) * KPAD0 + kc * 32 + part * 8) = u.v;
            }
        }
        __syncthreads();
    }
}

// ---------------------------------------------------------------------------
// Transpose+convert gate weights to [n][k] bf16 (x-part rows only), k padded.
// blocks 0..2: layer0 gate g (K=271 -> 288); blocks 3..5: layer1 gate g (K=128).
// ---------------------------------------------------------------------------
__global__ __launch_bounds__(256) void wt_kernel(
    const float* __restrict__ Wr0, const float* __restrict__ Wu0, const float* __restrict__ Wo0,
    const float* __restrict__ Wr1, const float* __restrict__ Wu1, const float* __restrict__ Wo1,
    unsigned short* __restrict__ Wt0, unsigned short* __restrict__ Wt1)
{
    const int blk = blockIdx.x;
    const int layer = blk / 3, g = blk % 3;
    const int tid = threadIdx.x;
    const float* __restrict__ W =
        (layer == 0) ? ((g == 0) ? Wr0 : (g == 1) ? Wu0 : Wo0)
                     : ((g == 0) ? Wr1 : (g == 1) ? Wu1 : Wo1);
    const int Kp   = (layer == 0) ? KPAD0 : KPAD1;
    const int Ksrc = (layer == 0) ? IN_CH : HID;
    unsigned short* __restrict__ out =
        (layer == 0) ? (Wt0 + (size_t)g * HID * KPAD0) : (Wt1 + (size_t)g * HID * KPAD1);

    for (int n = 0; n < HID; ++n) {
        for (int k = tid; k < Kp; k += 256) {
            float v = (k < Ksrc) ? W[(size_t)k * HID + n] : 0.f;
            out[(size_t)n * Kp + k] = f2bf(v);
        }
    }
}

// ---------------------------------------------------------------------------
// Generic bf16 MFMA GEMM: XG[m][g*128+n] = sum_k A[m][k] * Wt[g][n][k] + bias_g[n]
// A: [M_TOT][Kpad] bf16 row-major. Wt: [n][Kpad] bf16 per gate.
// Block: 256 threads (4 waves), tile 128m x 128n, blockIdx.y = gate.
// ---------------------------------------------------------------------------
__global__ __launch_bounds__(256) void gemm_xg(
    const unsigned short* __restrict__ A,
    const unsigned short* __restrict__ Wt,
    const float* __restrict__ br, const float* __restrict__ bu, const float* __restrict__ bo,
    float* __restrict__ XG, int Kpad)
{
    const int g = blockIdx.y;
    const float* __restrict__ bias = (g == 0) ? br : (g == 1) ? bu : bo;
    const unsigned short* __restrict__ B = Wt + (size_t)g * HID * Kpad;

    __shared__ unsigned short As[128 * 40];   // 32k + 8 pad per row
    __shared__ unsigned short Bs[128 * 40];

    const int tid   = threadIdx.x;
    const int wave  = tid >> 6;
    const int lane  = tid & 63;
    const int l15   = lane & 15;
    const int quad  = lane >> 4;
    const int mhalf = wave >> 1;
    const int nhalf = wave & 1;
    const size_t m0 = (size_t)blockIdx.x * 128;

    floatx4 acc[4][4];
#pragma unroll
    for (int im = 0; im < 4; ++im)
#pragma unroll
        for (int in = 0; in < 4; ++in) acc[im][in] = (floatx4)0.f;

    const int r0 = tid >> 2, p0 = tid & 3;            // task 0
    const int r1 = (tid + 256) >> 2, p1 = tid & 3;    // task 1

    const int ksteps = Kpad >> 5;
    for (int kt = 0; kt < ksteps; ++kt) {
        if (kt) __syncthreads();
        const int kb = kt * 32;
        // stage A (128 x 32) and B (128 x 32), 16B chunks
        uint4 va0 = *(const uint4*)(A + (m0 + r0) * Kpad + kb + p0 * 8);
        uint4 va1 = *(const uint4*)(A + (m0 + r1) * Kpad + kb + p1 * 8);
        uint4 vb0 = *(const uint4*)(B + (size_t)r0 * Kpad + kb + p0 * 8);
        uint4 vb1 = *(const uint4*)(B + (size_t)r1 * Kpad + kb + p1 * 8);
        *(uint4*)(As + r0 * 40 + p0 * 8) = va0;
        *(uint4*)(As + r1 * 40 + p1 * 8) = va1;
        *(uint4*)(Bs + r0 * 40 + p0 * 8) = vb0;
        *(uint4*)(Bs + r1 * 40 + p1 * 8) = vb1;
        __syncthreads();

        short8 af[4], bf[4];
#pragma unroll
        for (int im = 0; im < 4; ++im)
            af[im] = *(const short8*)(As + (mhalf * 64 + im * 16 + l15) * 40 + quad * 8);
#pragma unroll
        for (int in = 0; in < 4; ++in)
            bf[in] = *(const short8*)(Bs + (nhalf * 64 + in * 16 + l15) * 40 + quad * 8);
#pragma unroll
        for (int im = 0; im < 4; ++im)
#pragma unroll
            for (int in = 0; in < 4; ++in)
                acc[im][in] = __builtin_amdgcn_mfma_f32_16x16x32_bf16(
                    af[im], bf[in], acc[im][in], 0, 0, 0);
    }

    // epilogue: add bias, store fp32
    float bv[4];
#pragma unroll
    for (int in = 0; in < 4; ++in) bv[in] = bias[nhalf * 64 + in * 16 + l15];
#pragma unroll
    for (int im = 0; im < 4; ++im) {
#pragma unroll
        for (int v = 0; v < 4; ++v) {
            size_t m = m0 + mhalf * 64 + im * 16 + quad * 4 + v;
            float* row = XG + m * 384 + g * HID;
#pragma unroll
            for (int in = 0; in < 4; ++in)
                row[nhalf * 64 + in * 16 + l15] = acc[im][in][v] + bv[in];
        }
    }
}

// ---------------------------------------------------------------------------
// Layer-0 recurrence. One block per batch element, 512 threads.
// Writes H0 as bf16 [b*281+t][128] for the layer-1 MFMA GEMM.
// ---------------------------------------------------------------------------
__global__ __launch_bounds__(512, 2) void gru_l0(
    const float* __restrict__ Wr, const float* __restrict__ Wu, const float* __restrict__ Wo,
    const float* __restrict__ XG, unsigned short* __restrict__ H0bf)
{
    const int b = blockIdx.x;
    const int i = threadIdx.x;
    const int j = i & 127;
    const int q = i >> 7;

    __shared__ float h0[HID];
    __shared__ float rh[HID];
    __shared__ float ua[HID];
    __shared__ float P[2][4][HID];

    float wr[32], wu[32], wo[32];
    const int kbase = IN_CH + q * 32;
#pragma unroll
    for (int kk = 0; kk < 32; ++kk) {
        wr[kk] = Wr[(kbase + kk) * HID + j];
        wu[kk] = Wu[(kbase + kk) * HID + j];
        wo[kk] = Wo[(kbase + kk) * HID + j];
    }
    if (i < HID) h0[i] = 0.f;
    __syncthreads();

    for (int t = 0; t < SEQ; ++t) {
        const float* __restrict__ xg = XG + ((size_t)b * SEQ + t) * 384;

        float hreg[32];
        {
            const float4* hp = (const float4*)(h0 + q * 32);
#pragma unroll
            for (int r = 0; r < 8; ++r) {
                float4 v = hp[r];
                hreg[4 * r] = v.x; hreg[4 * r + 1] = v.y;
                hreg[4 * r + 2] = v.z; hreg[4 * r + 3] = v.w;
            }
        }
        float pr = 0.f, pu = 0.f;
#pragma unroll
        for (int kk = 0; kk < 32; ++kk) {
            pr += wr[kk] * hreg[kk];
            pu += wu[kk] * hreg[kk];
        }
        P[0][q][j] = pr;
        P[1][q][j] = pu;
        __syncthreads();

        if (i < 256) {
            int gg = i >> 7, jj = i & 127;
            float s = P[gg][0][jj] + P[gg][1][jj] + P[gg][2][jj] + P[gg][3][jj]
                    + xg[gg * HID + jj];
            float v = 1.f / (1.f + __expf(-s));
            if (gg == 0) rh[jj] = v * h0[jj];
            else         ua[jj] = v;
        }
        __syncthreads();

        float rreg[32];
        {
            const float4* rp = (const float4*)(rh + q * 32);
#pragma unroll
            for (int r = 0; r < 8; ++r) {
                float4 v = rp[r];
                rreg[4 * r] = v.x; rreg[4 * r + 1] = v.y;
                rreg[4 * r + 2] = v.z; rreg[4 * r + 3] = v.w;
            }
        }
        float po = 0.f;
#pragma unroll
        for (int kk = 0; kk < 32; ++kk) po += wo[kk] * rreg[kk];
        P[0][q][j] = po;
        __syncthreads();

        if (i < HID) {
            float s = P[0][0][i] + P[0][1][i] + P[0][2][i] + P[0][3][i]
                    + xg[2 * HID + i];
            float o = tanhf(s);
            float hn = h0[i] + ua[i] * (o - h0[i]);
            h0[i] = hn;
            H0bf[((size_t)b * SEQ + t) * HID + i] = f2bf(hn);
        }
        __syncthreads();
    }
}

// ---------------------------------------------------------------------------
// Layer-1 recurrence + fused classifier.
// ---------------------------------------------------------------------------
__global__ __launch_bounds__(512, 2) void gru_l1(
    const float* __restrict__ Wr, const float* __restrict__ Wu, const float* __restrict__ Wo,
    const float* __restrict__ XG,
    const float* __restrict__ Wfc, const float* __restrict__ bfc,
    float* __restrict__ out)
{
    const int b = blockIdx.x;
    const int i = threadIdx.x;
    const int j = i & 127;
    const int q = i >> 7;

    __shared__ float h1[HID];
    __shared__ float rh[HID];
    __shared__ float ua[HID];
    __shared__ float P[2][4][HID];

    float wr[32], wu[32], wo[32];
    const int kbase = HID + q * 32;
#pragma unroll
    for (int kk = 0; kk < 32; ++kk) {
        wr[kk] = Wr[(kbase + kk) * HID + j];
        wu[kk] = Wu[(kbase + kk) * HID + j];
        wo[kk] = Wo[(kbase + kk) * HID + j];
    }
    if (i < HID) h1[i] = 0.f;
    __syncthreads();

    for (int t = 0; t < SEQ; ++t) {
        const float* __restrict__ xg = XG + ((size_t)b * SEQ + t) * 384;

        float hreg[32];
        {
            const float4* hp = (const float4*)(h1 + q * 32);
#pragma unroll
            for (int r = 0; r < 8; ++r) {
                float4 v = hp[r];
                hreg[4 * r] = v.x; hreg[4 * r + 1] = v.y;
                hreg[4 * r + 2] = v.z; hreg[4 * r + 3] = v.w;
            }
        }
        float pr = 0.f, pu = 0.f;
#pragma unroll
        for (int kk = 0; kk < 32; ++kk) {
            pr += wr[kk] * hreg[kk];
            pu += wu[kk] * hreg[kk];
        }
        P[0][q][j] = pr;
        P[1][q][j] = pu;
        __syncthreads();

        if (i < 256) {
            int gg = i >> 7, jj = i & 127;
            float s = P[gg][0][jj] + P[gg][1][jj] + P[gg][2][jj] + P[gg][3][jj]
                    + xg[gg * HID + jj];
            float v = 1.f / (1.f + __expf(-s));
            if (gg == 0) rh[jj] = v * h1[jj];
            else         ua[jj] = v;
        }
        __syncthreads();

        float rreg[32];
        {
            const float4* rp = (const float4*)(rh + q * 32);
#pragma unroll
            for (int r = 0; r < 8; ++r) {
                float4 v = rp[r];
                rreg[4 * r] = v.x; rreg[4 * r + 1] = v.y;
                rreg[4 * r + 2] = v.z; rreg[4 * r + 3] = v.w;
            }
        }
        float po = 0.f;
#pragma unroll
        for (int kk = 0; kk < 32; ++kk) po += wo[kk] * rreg[kk];
        P[0][q][j] = po;
        __syncthreads();

        if (i < HID) {
            float s = P[0][0][i] + P[0][1][i] + P[0][2][i] + P[0][3][i]
                    + xg[2 * HID + i];
            float o = tanhf(s);
            float hn = h1[i] + ua[i] * (o - h1[i]);
            h1[i] = hn;
        }
        __syncthreads();
    }

    // fused classifier: out[b,c] = sum_k h1[k] * Wfc[k,c] + bfc[c]
    const int c0 = i, c1 = i + 512, c2 = i + 1024;
    const int c3 = (i < NCLS - 1536) ? (i + 1536) : 0;
    float a0 = bfc[c0], a1 = bfc[c1], a2 = bfc[c2], a3 = bfc[c3];
#pragma unroll 4
    for (int k = 0; k < HID; ++k) {
        float hk = h1[k];
        const float* __restrict__ wrow = Wfc + (size_t)k * NCLS;
        a0 += hk * wrow[c0];
        a1 += hk * wrow[c1];
        a2 += hk * wrow[c2];
        a3 += hk * wrow[c3];
    }
    float* orow = out + (size_t)b * NCLS;
    orow[c0] = a0;
    orow[c1] = a1;
    orow[c2] = a2;
    if (i < NCLS - 1536) orow[i + 1536] = a3;
}

// ---------------------------------------------------------------------------
extern "C" void kernel_launch(void* const* d_in, const int* in_sizes, int n_in,
                              void* d_out, int out_size, void* d_ws, size_t ws_size,
                              hipStream_t stream)
{
    const float* X   = (const float*)d_in[0];
    const float* Wr0 = (const float*)d_in[1];
    const float* br0 = (const float*)d_in[2];
    const float* Wu0 = (const float*)d_in[3];
    const float* bu0 = (const float*)d_in[4];
    const float* Wo0 = (const float*)d_in[5];
    const float* bo0 = (const float*)d_in[6];
    const float* Wr1 = (const float*)d_in[7];
    const float* br1 = (const float*)d_in[8];
    const float* Wu1 = (const float*)d_in[9];
    const float* bu1 = (const float*)d_in[10];
    const float* Wo1 = (const float*)d_in[11];
    const float* bo1 = (const float*)d_in[12];
    const float* Wfc = (const float*)d_in[13];
    const float* bfc = (const float*)d_in[14];
    float* out = (float*)d_out;

    // workspace layout (bytes):
    //   XG fp32 : [M_TOT*384]            = 110,493,696
    //   Abf bf16: [M_TOT*288]            =  41,435,136   (H0bf overlaps: dead after gemm l0)
    //   Wt0 bf16: [3*128*288]            =     221,184
    //   Wt1 bf16: [3*128*128]            =      98,304
    // total ~152.25 MB
    char* ws = (char*)d_ws;
    float*          XG   = (float*)ws;
    unsigned short* Abf  = (unsigned short*)(ws + (size_t)M_TOT * 384 * 4);
    unsigned short* H0bf = Abf;   // reuse: Abf dead once gemm l0 completes
    unsigned short* Wt0  = (unsigned short*)(ws + (size_t)M_TOT * 384 * 4 + (size_t)M_TOT * KPAD0 * 2);
    unsigned short* Wt1  = Wt0 + (size_t)3 * HID * KPAD0;

    wt_kernel<<<dim3(6), 256, 0, stream>>>(Wr0, Wu0, Wo0, Wr1, Wu1, Wo1, Wt0, Wt1);
    xt_kernel<<<dim3(5, BATCH), 256, 0, stream>>>(X, Abf);
    gemm_xg  <<<dim3(M_TOT / 128, 3), 256, 0, stream>>>(Abf, Wt0, br0, bu0, bo0, XG, KPAD0);
    gru_l0   <<<dim3(BATCH), 512, 0, stream>>>(Wr0, Wu0, Wo0, XG, H0bf);
    gemm_xg  <<<dim3(M_TOT / 128, 3), 256, 0, stream>>>(H0bf, Wt1, br1, bu1, bo1, XG, KPAD1);
    gru_l1   <<<dim3(BATCH), 512, 0, stream>>>(Wr1, Wu1, Wo1, XG, Wfc, bfc, out);
}

// Round 3
// 790.060 us; speedup vs baseline: 2.2713x; 1.2784x over previous
//
#include <hip/hip_runtime.h>
#include <math.h>

#define HID    128
#define IN_CH  271
#define SEQ    281
#define NCLS   1854
#define BATCH  256
#define M_TOT  (SEQ * BATCH)          // 71936 = 562 * 128
#define KPAD0  288                    // 271 padded to 9*32
#define KPAD1  128

typedef __attribute__((ext_vector_type(8))) short short8;
typedef __attribute__((ext_vector_type(4))) float floatx4;

__device__ __forceinline__ unsigned short f2bf(float f) {
    union { float f; unsigned u; } v; v.f = f;
    unsigned u = v.u;
    u += 0x7FFF + ((u >> 16) & 1);        // RNE
    return (unsigned short)(u >> 16);
}

__device__ __forceinline__ float fast_sigmoid(float s) {
    return 1.f / (1.f + __expf(-s));
}
__device__ __forceinline__ float fast_tanh(float s) {
    float a = fabsf(s);
    float e = __expf(-2.f * a);
    float t = (1.f - e) / (1.f + e);
    return copysignf(t, s);
}

// ---------------------------------------------------------------------------
// Transpose+convert X: X[b][k][t] fp32 -> Abf[(b*281+t)*288 + k] bf16.
// ---------------------------------------------------------------------------
__global__ __launch_bounds__(256) void xt_kernel(
    const float* __restrict__ X, unsigned short* __restrict__ Abf)
{
    const int tb = blockIdx.x;            // 0..4, t-tile of 64
    const int b  = blockIdx.y;
    const int tid = threadIdx.x;
    const int t0 = tb * 64;
    const float* __restrict__ Xb = X + (size_t)b * (IN_CH * SEQ);

    __shared__ float Xl[32][65];

    for (int kc = 0; kc < KPAD0 / 32; ++kc) {
#pragma unroll
        for (int r = 0; r < 8; ++r) {
            int e = tid + 256 * r;
            int kk = e >> 6, tt = e & 63;
            int k = kc * 32 + kk, t = t0 + tt;
            Xl[kk][tt] = (k < IN_CH && t < SEQ) ? Xb[k * SEQ + t] : 0.f;
        }
        __syncthreads();
        {
            int tt = tid >> 2, part = tid & 3;
            int t = t0 + tt;
            if (t < SEQ) {
                union { unsigned short s[8]; uint4 v; } u;
#pragma unroll
                for (int i = 0; i < 8; ++i) u.s[i] = f2bf(Xl[part * 8 + i][tt]);
                *(uint4*)(Abf + ((size_t)b * SEQ + t) * KPAD0 + kc * 32 + part * 8) = u.v;
            }
        }
        __syncthreads();
    }
}

// ---------------------------------------------------------------------------
// Transpose+convert gate weights to [n][k] bf16 (x-part rows only), k padded.
// ---------------------------------------------------------------------------
__global__ __launch_bounds__(256) void wt_kernel(
    const float* __restrict__ Wr0, const float* __restrict__ Wu0, const float* __restrict__ Wo0,
    const float* __restrict__ Wr1, const float* __restrict__ Wu1, const float* __restrict__ Wo1,
    unsigned short* __restrict__ Wt0, unsigned short* __restrict__ Wt1)
{
    const int blk = blockIdx.x;
    const int layer = blk / 3, g = blk % 3;
    const int tid = threadIdx.x;
    const float* __restrict__ W =
        (layer == 0) ? ((g == 0) ? Wr0 : (g == 1) ? Wu0 : Wo0)
                     : ((g == 0) ? Wr1 : (g == 1) ? Wu1 : Wo1);
    const int Kp   = (layer == 0) ? KPAD0 : KPAD1;
    const int Ksrc = (layer == 0) ? IN_CH : HID;
    unsigned short* __restrict__ out =
        (layer == 0) ? (Wt0 + (size_t)g * HID * KPAD0) : (Wt1 + (size_t)g * HID * KPAD1);

    for (int n = 0; n < HID; ++n) {
        for (int k = tid; k < Kp; k += 256) {
            float v = (k < Ksrc) ? W[(size_t)k * HID + n] : 0.f;
            out[(size_t)n * Kp + k] = f2bf(v);
        }
    }
}

// ---------------------------------------------------------------------------
// bf16 MFMA GEMM: XG[m][g*128+n] = sum_k A[m][k]*Wt[g][n][k] + bias_g[n]
// ---------------------------------------------------------------------------
__global__ __launch_bounds__(256) void gemm_xg(
    const unsigned short* __restrict__ A,
    const unsigned short* __restrict__ Wt,
    const float* __restrict__ br, const float* __restrict__ bu, const float* __restrict__ bo,
    float* __restrict__ XG, int Kpad)
{
    const int g = blockIdx.y;
    const float* __restrict__ bias = (g == 0) ? br : (g == 1) ? bu : bo;
    const unsigned short* __restrict__ B = Wt + (size_t)g * HID * Kpad;

    __shared__ unsigned short As[128 * 40];
    __shared__ unsigned short Bs[128 * 40];

    const int tid   = threadIdx.x;
    const int wave  = tid >> 6;
    const int lane  = tid & 63;
    const int l15   = lane & 15;
    const int quad  = lane >> 4;
    const int mhalf = wave >> 1;
    const int nhalf = wave & 1;
    const size_t m0 = (size_t)blockIdx.x * 128;

    floatx4 acc[4][4];
#pragma unroll
    for (int im = 0; im < 4; ++im)
#pragma unroll
        for (int in = 0; in < 4; ++in) acc[im][in] = (floatx4)0.f;

    const int r0 = tid >> 2, p0 = tid & 3;
    const int r1 = (tid + 256) >> 2, p1 = tid & 3;

    const int ksteps = Kpad >> 5;
    for (int kt = 0; kt < ksteps; ++kt) {
        if (kt) __syncthreads();
        const int kb = kt * 32;
        uint4 va0 = *(const uint4*)(A + (m0 + r0) * Kpad + kb + p0 * 8);
        uint4 va1 = *(const uint4*)(A + (m0 + r1) * Kpad + kb + p1 * 8);
        uint4 vb0 = *(const uint4*)(B + (size_t)r0 * Kpad + kb + p0 * 8);
        uint4 vb1 = *(const uint4*)(B + (size_t)r1 * Kpad + kb + p1 * 8);
        *(uint4*)(As + r0 * 40 + p0 * 8) = va0;
        *(uint4*)(As + r1 * 40 + p1 * 8) = va1;
        *(uint4*)(Bs + r0 * 40 + p0 * 8) = vb0;
        *(uint4*)(Bs + r1 * 40 + p1 * 8) = vb1;
        __syncthreads();

        short8 af[4], bf[4];
#pragma unroll
        for (int im = 0; im < 4; ++im)
            af[im] = *(const short8*)(As + (mhalf * 64 + im * 16 + l15) * 40 + quad * 8);
#pragma unroll
        for (int in = 0; in < 4; ++in)
            bf[in] = *(const short8*)(Bs + (nhalf * 64 + in * 16 + l15) * 40 + quad * 8);
#pragma unroll
        for (int im = 0; im < 4; ++im)
#pragma unroll
            for (int in = 0; in < 4; ++in)
                acc[im][in] = __builtin_amdgcn_mfma_f32_16x16x32_bf16(
                    af[im], bf[in], acc[im][in], 0, 0, 0);
    }

    float bv[4];
#pragma unroll
    for (int in = 0; in < 4; ++in) bv[in] = bias[nhalf * 64 + in * 16 + l15];
#pragma unroll
    for (int im = 0; im < 4; ++im) {
#pragma unroll
        for (int v = 0; v < 4; ++v) {
            size_t m = m0 + mhalf * 64 + im * 16 + quad * 4 + v;
            float* row = XG + m * 384 + g * HID;
#pragma unroll
            for (int in = 0; in < 4; ++in)
                row[nhalf * 64 + in * 16 + l15] = acc[im][in][v] + bv[in];
        }
    }
}

// ---------------------------------------------------------------------------
// GRU recurrence, restructured: lane = jj*4+q (16 j-cols x 4 K-quarters per
// wave, 8 waves -> j=0..127). K-reduction = 2x shfl_xor (intra-wave).
// 2 barriers/step. xg prefetched one step ahead into registers.
// h/rh in bank-staggered LDS (word k + 4*(k>>5)): q-slices hit disjoint
// bank quads, 16-way broadcast per address (free).
// LAYER=0: rows IN_CH.. of W0, writes H0bf.  LAYER=1: rows HID.. of W1,
// fused classifier epilogue.
// ---------------------------------------------------------------------------
#define PADIDX(k) ((k) + 4 * ((k) >> 5))

template <int LAYER>
__global__ __launch_bounds__(512, 2) void gru_rec(
    const float* __restrict__ Wr, const float* __restrict__ Wu, const float* __restrict__ Wo,
    const float* __restrict__ XG, unsigned short* __restrict__ H0bf,
    const float* __restrict__ Wfc, const float* __restrict__ bfc,
    float* __restrict__ out)
{
    const int b    = blockIdx.x;
    const int tid  = threadIdx.x;
    const int wv   = tid >> 6;
    const int lane = tid & 63;
    const int jj   = lane >> 2;
    const int q    = lane & 3;
    const int j    = wv * 16 + jj;

    __shared__ float h_pad[140];
    __shared__ float rh_pad[140];
    __shared__ float h_fin[HID];

    // recurrent-part weight rows, held in registers
    float wr[32], wu[32], wo[32];
    const int kbase = (LAYER == 0 ? IN_CH : HID) + q * 32;
#pragma unroll
    for (int kk = 0; kk < 32; ++kk) {
        wr[kk] = Wr[(kbase + kk) * HID + j];
        wu[kk] = Wu[(kbase + kk) * HID + j];
        wo[kk] = Wo[(kbase + kk) * HID + j];
    }

    if (tid < 140) { h_pad[tid] = 0.f; rh_pad[tid] = 0.f; }

    float hj = 0.f;                    // this j's state (replicated over q)
    const float* __restrict__ xg0 = XG + ((size_t)b * SEQ) * 384;
    float xr = xg0[j], xu = xg0[128 + j], xo = xg0[256 + j];
    __syncthreads();

    for (int t = 0; t < SEQ; ++t) {
        // prefetch xg for t+1 (clamped) — consumed next iteration
        const int tn = (t + 1 < SEQ) ? t + 1 : t;
        const float* __restrict__ xgn = XG + ((size_t)b * SEQ + tn) * 384;
        float nr = xgn[j], nu = xgn[128 + j], no = xgn[256 + j];

        // ---- phase 1: r,u dot products over this lane's K-quarter
        float4 h4[8];
        {
            const float4* hp = (const float4*)(h_pad + q * 36);
#pragma unroll
            for (int rr = 0; rr < 8; ++rr) h4[rr] = hp[rr];
        }
        float pr = 0.f, pu = 0.f;
#pragma unroll
        for (int rr = 0; rr < 8; ++rr) {
            float4 v = h4[rr];
            pr += wr[4*rr]*v.x + wr[4*rr+1]*v.y + wr[4*rr+2]*v.z + wr[4*rr+3]*v.w;
            pu += wu[4*rr]*v.x + wu[4*rr+1]*v.y + wu[4*rr+2]*v.z + wu[4*rr+3]*v.w;
        }
        pr += __shfl_xor(pr, 1); pr += __shfl_xor(pr, 2);
        pu += __shfl_xor(pu, 1); pu += __shfl_xor(pu, 2);

        float rg = fast_sigmoid(pr + xr);
        float ug = fast_sigmoid(pu + xu);
        if (q == 0) rh_pad[PADIDX(j)] = rg * hj;
        __syncthreads();

        // ---- phase 2: o dot product over rh
        float4 r4[8];
        {
            const float4* rp = (const float4*)(rh_pad + q * 36);
#pragma unroll
            for (int rr = 0; rr < 8; ++rr) r4[rr] = rp[rr];
        }
        float po = 0.f;
#pragma unroll
        for (int rr = 0; rr < 8; ++rr) {
            float4 v = r4[rr];
            po += wo[4*rr]*v.x + wo[4*rr+1]*v.y + wo[4*rr+2]*v.z + wo[4*rr+3]*v.w;
        }
        po += __shfl_xor(po, 1); po += __shfl_xor(po, 2);

        float og = fast_tanh(po + xo);
        hj = hj + ug * (og - hj);
        if (q == 0) h_pad[PADIDX(j)] = hj;
        if (LAYER == 0) {
            if (q == 1) H0bf[((size_t)b * SEQ + t) * HID + j] = f2bf(hj);
        }
        xr = nr; xu = nu; xo = no;
        __syncthreads();
    }

    if (LAYER == 1) {
        // publish final h1 densely, then fused classifier
        if (q == 0) h_fin[j] = hj;
        __syncthreads();

        const int c0 = tid, c1 = tid + 512, c2 = tid + 1024;
        const int c3 = (tid < NCLS - 1536) ? (tid + 1536) : 0;
        float a0 = bfc[c0], a1 = bfc[c1], a2 = bfc[c2], a3 = bfc[c3];
#pragma unroll 4
        for (int k = 0; k < HID; ++k) {
            float hk = h_fin[k];
            const float* __restrict__ wrow = Wfc + (size_t)k * NCLS;
            a0 += hk * wrow[c0];
            a1 += hk * wrow[c1];
            a2 += hk * wrow[c2];
            a3 += hk * wrow[c3];
        }
        float* orow = out + (size_t)b * NCLS;
        orow[c0] = a0;
        orow[c1] = a1;
        orow[c2] = a2;
        if (tid < NCLS - 1536) orow[tid + 1536] = a3;
    }
}

// ---------------------------------------------------------------------------
extern "C" void kernel_launch(void* const* d_in, const int* in_sizes, int n_in,
                              void* d_out, int out_size, void* d_ws, size_t ws_size,
                              hipStream_t stream)
{
    const float* X   = (const float*)d_in[0];
    const float* Wr0 = (const float*)d_in[1];
    const float* br0 = (const float*)d_in[2];
    const float* Wu0 = (const float*)d_in[3];
    const float* bu0 = (const float*)d_in[4];
    const float* Wo0 = (const float*)d_in[5];
    const float* bo0 = (const float*)d_in[6];
    const float* Wr1 = (const float*)d_in[7];
    const float* br1 = (const float*)d_in[8];
    const float* Wu1 = (const float*)d_in[9];
    const float* bu1 = (const float*)d_in[10];
    const float* Wo1 = (const float*)d_in[11];
    const float* bo1 = (const float*)d_in[12];
    const float* Wfc = (const float*)d_in[13];
    const float* bfc = (const float*)d_in[14];
    float* out = (float*)d_out;

    char* ws = (char*)d_ws;
    float*          XG   = (float*)ws;                                         // 110.5 MB
    unsigned short* Abf  = (unsigned short*)(ws + (size_t)M_TOT * 384 * 4);    //  41.4 MB
    unsigned short* H0bf = Abf;   // reuse: Abf dead once gemm l0 completes
    unsigned short* Wt0  = (unsigned short*)(ws + (size_t)M_TOT * 384 * 4 + (size_t)M_TOT * KPAD0 * 2);
    unsigned short* Wt1  = Wt0 + (size_t)3 * HID * KPAD0;

    wt_kernel<<<dim3(6), 256, 0, stream>>>(Wr0, Wu0, Wo0, Wr1, Wu1, Wo1, Wt0, Wt1);
    xt_kernel<<<dim3(5, BATCH), 256, 0, stream>>>(X, Abf);
    gemm_xg  <<<dim3(M_TOT / 128, 3), 256, 0, stream>>>(Abf, Wt0, br0, bu0, bo0, XG, KPAD0);
    gru_rec<0><<<dim3(BATCH), 512, 0, stream>>>(Wr0, Wu0, Wo0, XG, H0bf, nullptr, nullptr, nullptr);
    gemm_xg  <<<dim3(M_TOT / 128, 3), 256, 0, stream>>>(H0bf, Wt1, br1, bu1, bo1, XG, KPAD1);
    gru_rec<1><<<dim3(BATCH), 512, 0, stream>>>(Wr1, Wu1, Wo1, XG, nullptr, Wfc, bfc, out);
}